// Round 3
// baseline (247.409 us; speedup 1.0000x reference)
//
#include <hip/hip_runtime.h>
#include <hip/hip_bf16.h>

using bf16 = __hip_bfloat16;

// ---------- helpers ----------
__device__ __forceinline__ float fexp(float x)  { return __builtin_amdgcn_exp2f(x * 1.44269504f); }
__device__ __forceinline__ float frcp(float x)  { return __builtin_amdgcn_rcpf(x); }
__device__ __forceinline__ float sigm(float x)  { return frcp(1.f + fexp(-x)); }
__device__ __forceinline__ float tanh_f(float x){ return 1.f - 2.f * frcp(1.f + fexp(2.f * x)); }

// sizes
#define B_   1024
#define K_   160
#define GI_STEP (B_ * 36)   // elements per k-slice of gi1 (bf16): 36864

// ws layout (bytes): gi1 bf16 [160][1024][36] @ 0        (11,796,480)
//                    pegi f32 [160][36]       @ 11796480 (23,040)
// total 11.82 MB. hout lives in d_out (in-place decode).
#define OFF_PEGI 11796480

// ---------------------------------------------------------------
// Kernel 1: encoder + input-gate precompute (all-parallel).
// gi1[k][b][r] = relu(x[b,k*12:+12] @ encW[k] + encb[k]) @ Wih^T + bih (+bhh for r,z rows)
// pegi[k][r]   = (pos_enc[k] + sin(k)) @ Wih^T   (gi delta for GRU2; channel_enc col is sin(k))
// grid (4, 160) x 256 threads
// ---------------------------------------------------------------
__global__ __launch_bounds__(256) void k_encode(
    const float* __restrict__ x, const float* __restrict__ encW, const float* __restrict__ encb,
    const float* __restrict__ Wih, const float* __restrict__ bih, const float* __restrict__ bhh,
    bf16* __restrict__ gi1, float* __restrict__ pegi)
{
    const int k = blockIdx.y;
    const int t = threadIdx.x;
    const int b = blockIdx.x * 256 + t;

    __shared__ float sW[144];    // encW[k][i][o]
    __shared__ float sbm[12];    // encb[k]
    __shared__ float sWih[432];  // Wih[r][o]
    __shared__ float sbih[36];   // bih (+bhh for rows 0..23)
    __shared__ float spet[12];   // pos_enc[k] + sin(k)

    if (t < 144) sW[t]  = encW[k * 144 + t];
    if (t < 12)  sbm[t] = encb[k * 12 + t];
    for (int i = t; i < 432; i += 256) sWih[i] = Wih[i];
    if (t < 36)  sbih[t] = bih[t] + (t < 24 ? bhh[t] : 0.f);
    if (t < 12) {
        int m = t >> 1;
        float div = __expf((float)(2 * m) * (-0.7675283643313489f)); // -ln(10000)/12
        float ang = (float)k * div;
        spet[t] = ((t & 1) ? cosf(ang) : sinf(ang)) + sinf((float)k);
    }
    __syncthreads();
    if (t < 36 && blockIdx.x == 0) {
        float s = 0.f;
        #pragma unroll
        for (int o = 0; o < 12; o++) s = fmaf(spet[o], sWih[t * 12 + o], s);
        pegi[k * 36 + t] = s;
    }

    // x[b, k*12 .. +12): 16B-aligned (k*48, b*7680 both %16==0)
    const float4* xp = reinterpret_cast<const float4*>(x + (size_t)b * 1920 + k * 12);
    float4 a0 = xp[0], a1 = xp[1], a2 = xp[2];
    float xv[12] = {a0.x,a0.y,a0.z,a0.w, a1.x,a1.y,a1.z,a1.w, a2.x,a2.y,a2.z,a2.w};

    float xs[12];
    #pragma unroll
    for (int o = 0; o < 12; o++) {
        float s = sbm[o];
        #pragma unroll
        for (int i = 0; i < 12; i++) s = fmaf(xv[i], sW[i * 12 + o], s);
        xs[o] = fmaxf(s, 0.f);
    }

    bf16* g1 = gi1 + (size_t)k * GI_STEP + (size_t)b * 36;
    #pragma unroll
    for (int r = 0; r < 36; r++) {
        float s = sbih[r];
        #pragma unroll
        for (int o = 0; o < 12; o++) s = fmaf(xs[o], sWih[r * 12 + o], s);
        g1[r] = (bf16)s;
    }
}

// ---------------------------------------------------------------
// Kernel 2: the two sequential GRU passes (the critical chain).
// 1 wave/block, 16 lanes per batch element (lane j<12 owns unit j),
// 4 batches/wave, 256 blocks -> 1024 chains, ~1 wave/CU.
// GRU2 input gates = gi1 + pegi[k] (LDS). h broadcast via __shfl.
// GRU2 hidden states written to hout == d_out ([b][k][12], f32).
// ---------------------------------------------------------------
__global__ __launch_bounds__(64) void k_recur(
    const float* __restrict__ Whh, const float* __restrict__ bhh,
    const bf16* __restrict__ gi1, const float* __restrict__ pegi,
    float* __restrict__ hout)
{
    __shared__ float spe[5760];
    const int lane = threadIdx.x;
    for (int i = lane; i < 5760; i += 64) spe[i] = pegi[i];

    const int g  = lane >> 4;
    const int j  = lane & 15;
    const int ju = (j < 12) ? j : 0;
    const int b  = blockIdx.x * 4 + g;
    const int src = lane & ~15;

    float Wr[12], Wz[12], Wn[12];
    #pragma unroll
    for (int d = 0; d < 12; d++) {
        Wr[d] = Whh[ju * 12 + d];
        Wz[d] = Whh[(12 + ju) * 12 + d];
        Wn[d] = Whh[(24 + ju) * 12 + d];
    }
    const float bn = bhh[24 + ju];
    __syncthreads();

    float h[12];
    #pragma unroll
    for (int d = 0; d < 12; d++) h[d] = 0.f;
    float hself = 0.f;

    const bf16* gp = gi1 + (size_t)b * 36;

    // ---- GRU1 (only final h needed) ----
    float gr = (float)gp[ju], gz = (float)gp[ju + 12], gn = (float)gp[ju + 24];
    for (int k = 0; k < 160; k++) {
        const int kp = (k < 159) ? (k + 1) : 159;            // clamped prefetch
        const bf16* nb = gp + (size_t)kp * GI_STEP;
        float pr = (float)nb[ju], pz = (float)nb[ju + 12], pn = (float)nb[ju + 24];
        float hr = 0.f, hz = 0.f, hn = bn;
        #pragma unroll
        for (int d = 0; d < 12; d++) {
            hr = fmaf(Wr[d], h[d], hr);
            hz = fmaf(Wz[d], h[d], hz);
            hn = fmaf(Wn[d], h[d], hn);
        }
        float r = sigm(gr + hr);
        float z = sigm(gz + hz);
        float n = tanh_f(fmaf(r, hn, gn));
        float hj = fmaf(z, hself - n, n);     // (1-z)*n + z*h
        hself = hj;
        #pragma unroll
        for (int d = 0; d < 12; d++) h[d] = __shfl(hj, src + d, 64);
        gr = pr; gz = pz; gn = pn;
    }

    // ---- GRU2 (emit h every step) ----
    gr = (float)gp[ju]      + spe[ju];
    gz = (float)gp[ju + 12] + spe[ju + 12];
    gn = (float)gp[ju + 24] + spe[ju + 24];
    float* ho = hout + (size_t)b * 1920;      // [b][k][12]
    for (int k = 0; k < 160; k++) {
        const int kp = (k < 159) ? (k + 1) : 159;
        const bf16* nb = gp + (size_t)kp * GI_STEP;
        float pr = (float)nb[ju]      + spe[kp * 36 + ju];
        float pz = (float)nb[ju + 12] + spe[kp * 36 + ju + 12];
        float pn = (float)nb[ju + 24] + spe[kp * 36 + ju + 24];
        float hr = 0.f, hz = 0.f, hn = bn;
        #pragma unroll
        for (int d = 0; d < 12; d++) {
            hr = fmaf(Wr[d], h[d], hr);
            hz = fmaf(Wz[d], h[d], hz);
            hn = fmaf(Wn[d], h[d], hn);
        }
        float r = sigm(gr + hr);
        float z = sigm(gz + hz);
        float n = tanh_f(fmaf(r, hn, gn));
        float hj = fmaf(z, hself - n, n);
        hself = hj;
        if (j < 12) ho[k * 12 + j] = hj;
        #pragma unroll
        for (int d = 0; d < 12; d++) h[d] = __shfl(hj, src + d, 64);
        gr = pr; gz = pz; gn = pn;
    }
}

// ---------------------------------------------------------------
// Kernel 3: decoder, in-place on d_out.
// Per k: fold W1@W2 -> Wc (12x12), b1@W2+b2 -> bc (12),
// then out[b, k*12+o] = h[b,k,:]@Wc + bc  (h read from the same slots).
// grid 160 x 640 threads.
// ---------------------------------------------------------------
__global__ __launch_bounds__(640) void k_decode(
    const float* __restrict__ W1, const float* __restrict__ b1,
    const float* __restrict__ W2, const float* __restrict__ b2,
    float* __restrict__ out)
{
    const int k = blockIdx.x, t = threadIdx.x;
    __shared__ float part[156][4];
    __shared__ float sWc[144];   // [d][o]
    __shared__ float sbc[12];

    const int p = t >> 2, q = t & 3;
    if (p < 156) {
        const float* va = (p < 144) ? (W1 + (size_t)k * 12288 + (size_t)(p / 12) * 1024)
                                    : (b1 + (size_t)k * 1024);
        const int o = (p < 144) ? (p % 12) : (p - 144);
        const float* vb = W2 + (size_t)k * 12288 + o;
        float s = 0.f;
        const int h0 = q * 256;
        for (int h = h0; h < h0 + 256; h++)
            s = fmaf(va[h], vb[h * 12], s);
        part[p][q] = s;
    }
    __syncthreads();
    if (t < 144)      sWc[t] = part[t][0] + part[t][1] + part[t][2] + part[t][3];
    else if (t < 156) sbc[t - 144] = part[t][0] + part[t][1] + part[t][2] + part[t][3]
                                     + b2[k * 12 + (t - 144)];
    __syncthreads();

    for (int bb = t; bb < 1024; bb += 640) {
        float* hp = out + (size_t)bb * 1920 + k * 12;
        const float4* h4 = reinterpret_cast<const float4*>(hp);
        float4 a0 = h4[0], a1 = h4[1], a2 = h4[2];
        float hv[12] = {a0.x,a0.y,a0.z,a0.w, a1.x,a1.y,a1.z,a1.w, a2.x,a2.y,a2.z,a2.w};
        float ov[12];
        #pragma unroll
        for (int o = 0; o < 12; o++) {
            float s = sbc[o];
            #pragma unroll
            for (int d = 0; d < 12; d++) s = fmaf(hv[d], sWc[d * 12 + o], s);
            ov[o] = s;
        }
        float4* o4 = reinterpret_cast<float4*>(hp);
        o4[0] = make_float4(ov[0], ov[1], ov[2], ov[3]);
        o4[1] = make_float4(ov[4], ov[5], ov[6], ov[7]);
        o4[2] = make_float4(ov[8], ov[9], ov[10], ov[11]);
    }
}

// ---------------------------------------------------------------
extern "C" void kernel_launch(void* const* d_in, const int* in_sizes, int n_in,
                              void* d_out, int out_size, void* d_ws, size_t ws_size,
                              hipStream_t stream)
{
    const float* x    = (const float*)d_in[0];
    const float* encW = (const float*)d_in[1];
    const float* encb = (const float*)d_in[2];
    const float* Wih  = (const float*)d_in[3];
    const float* Whh  = (const float*)d_in[4];
    const float* bih  = (const float*)d_in[5];
    const float* bhh  = (const float*)d_in[6];
    const float* W1   = (const float*)d_in[7];
    const float* b1   = (const float*)d_in[8];
    const float* W2   = (const float*)d_in[9];
    const float* b2   = (const float*)d_in[10];
    float* out = (float*)d_out;

    char* ws = (char*)d_ws;
    bf16*  gi1  = (bf16*)(ws);
    float* pegi = (float*)(ws + OFF_PEGI);

    k_encode<<<dim3(4, 160), 256, 0, stream>>>(x, encW, encb, Wih, bih, bhh, gi1, pegi);
    k_recur <<<dim3(256),    64,  0, stream>>>(Whh, bhh, gi1, pegi, out);
    k_decode<<<dim3(160),    640, 0, stream>>>(W1, b1, W2, b2, out);
}

// Round 5
// 210.513 us; speedup vs baseline: 1.1753x; 1.1753x over previous
//
#include <hip/hip_runtime.h>
#include <hip/hip_bf16.h>

using bf16 = __hip_bfloat16;

#define C1 1.44269504f   // log2(e)
#define C2 2.88539008f   // 2*log2(e)

__device__ __forceinline__ float fexp2(float x) { return __builtin_amdgcn_exp2f(x); }
__device__ __forceinline__ float frcp(float x)  { return __builtin_amdgcn_rcpf(x); }
// sigmoid(v) with x = C1*v already applied upstream
__device__ __forceinline__ float sigm2(float x) { return frcp(1.f + fexp2(-x)); }
// tanh(y) with x = C2*y already applied upstream
__device__ __forceinline__ float tanh2(float x) { return 1.f - 2.f * frcp(1.f + fexp2(x)); }

__device__ __forceinline__ float bf2f(unsigned int u) {
    union { unsigned int u; float f; } c; c.u = u << 16; return c.f;
}
__device__ __forceinline__ unsigned int f2bfbits(float f) {  // RNE float->bf16 bits
    union { float f; unsigned int u; } c; c.f = f;
    return (c.u + 0x7fffu + ((c.u >> 16) & 1u)) >> 16;
}

// gi layout: [k][b][12] of uint2 {lo = r|z<<16, hi = n} (bf16 bits, pre-scaled C1/C1/C2)
#define KSTR 12288   // uint2 per k-slice (1024*12)
// ws layout: gi @0 (15,728,640 B) | pegi float4[160][12] @15,728,640 (30,720 B)
//            Wcg float[160][156]  @15,759,360 (99,840 B)   => 15.86 MB total
#define OFF_PEGI 15728640
#define OFF_WC   15759360

// ---------------------------------------------------------------
// Kernel 1: encoder + input-gate precompute. grid (4,160) x 256
// ---------------------------------------------------------------
__global__ __launch_bounds__(256) void k_encode(
    const float* __restrict__ x, const float* __restrict__ encW, const float* __restrict__ encb,
    const float* __restrict__ Wih, const float* __restrict__ bih, const float* __restrict__ bhh,
    uint2* __restrict__ gi, float4* __restrict__ pegi)
{
    const int k = blockIdx.y, t = threadIdx.x;
    const int b = blockIdx.x * 256 + t;

    __shared__ float sW[144], sbm[12], sWih[432], sbih[36], spet[12];
    if (t < 144) sW[t]  = encW[k * 144 + t];
    if (t < 12)  sbm[t] = encb[k * 12 + t];
    for (int i = t; i < 432; i += 256) sWih[i] = Wih[i];
    if (t < 36)  sbih[t] = bih[t] + (t < 24 ? bhh[t] : 0.f);
    if (t < 12) {
        int m = t >> 1;
        float div = __expf((float)(2 * m) * (-0.7675283643313489f)); // -ln(10000)/12
        float ang = (float)k * div;
        spet[t] = ((t & 1) ? cosf(ang) : sinf(ang)) + sinf((float)k);
    }
    __syncthreads();
    if (t < 12 && blockIdx.x == 0) {
        float sr = 0.f, sz = 0.f, sn = 0.f;
        #pragma unroll
        for (int o = 0; o < 12; o++) {
            sr = fmaf(spet[o], sWih[t * 12 + o], sr);
            sz = fmaf(spet[o], sWih[(12 + t) * 12 + o], sz);
            sn = fmaf(spet[o], sWih[(24 + t) * 12 + o], sn);
        }
        pegi[k * 12 + t] = make_float4(C1 * sr, C1 * sz, C2 * sn, 0.f);
    }

    const float4* xp = reinterpret_cast<const float4*>(x + (size_t)b * 1920 + k * 12);
    float4 a0 = xp[0], a1 = xp[1], a2 = xp[2];
    float xv[12] = {a0.x,a0.y,a0.z,a0.w, a1.x,a1.y,a1.z,a1.w, a2.x,a2.y,a2.z,a2.w};

    float xs[12];
    #pragma unroll
    for (int o = 0; o < 12; o++) {
        float s = sbm[o];
        #pragma unroll
        for (int i = 0; i < 12; i++) s = fmaf(xv[i], sW[i * 12 + o], s);
        xs[o] = fmaxf(s, 0.f);
    }

    uint2* g = gi + ((size_t)k * 1024 + b) * 12;
    #pragma unroll
    for (int j = 0; j < 12; j++) {
        float sr = sbih[j], sz = sbih[12 + j], sn = sbih[24 + j];
        #pragma unroll
        for (int o = 0; o < 12; o++) {
            sr = fmaf(xs[o], sWih[j * 12 + o], sr);
            sz = fmaf(xs[o], sWih[(12 + j) * 12 + o], sz);
            sn = fmaf(xs[o], sWih[(24 + j) * 12 + o], sn);
        }
        g[j] = make_uint2(f2bfbits(C1 * sr) | (f2bfbits(C1 * sz) << 16), f2bfbits(C2 * sn));
    }
}

// ---------------------------------------------------------------
// Kernel 2: the two GRU passes. 256 blocks x 64. 4 chains/wave,
// 16 lanes/chain. Depth-8 register prefetch of gi (+pegi for GRU2).
// ---------------------------------------------------------------
__global__ __launch_bounds__(64) void k_recur(
    const float* __restrict__ Whh, const float* __restrict__ bhh,
    const uint2* __restrict__ gi, const float4* __restrict__ pegi,
    float* __restrict__ hout)
{
    const int lane = threadIdx.x;
    const int g = lane >> 4, j = lane & 15;
    const int ju = (j < 12) ? j : 0;
    const int b = blockIdx.x * 4 + g;
    const int src = lane & ~15;

    float wr[12], wz[12], wn[12];
    #pragma unroll
    for (int d = 0; d < 12; d++) {
        wr[d] = C1 * Whh[ju * 12 + d];
        wz[d] = C1 * Whh[(12 + ju) * 12 + d];
        wn[d] = C2 * Whh[(24 + ju) * 12 + d];
    }
    const float bn = C2 * bhh[24 + ju];

    const uint2* gp = gi + (size_t)b * 12 + ju;

    float h[12];
    #pragma unroll
    for (int d = 0; d < 12; d++) h[d] = 0.f;
    float hself = 0.f;

    uint2 buf[8];
    #pragma unroll
    for (int i = 0; i < 8; i++) buf[i] = gp[(size_t)i * KSTR];

    // ---- GRU1 (only final h needed) ----
    for (int ko = 0; ko < 160; ko += 8) {
        #pragma unroll
        for (int i = 0; i < 8; i++) {
            const int k = ko + i;
            float gr = bf2f(buf[i].x & 0xffffu);
            float gz = bf2f(buf[i].x >> 16);
            float gn = bf2f(buf[i].y & 0xffffu);
            int kp = k + 8; kp = (kp > 159) ? 159 : kp;
            buf[i] = gp[(size_t)kp * KSTR];                 // 8-deep prefetch
            float hr = 0.f, hz = 0.f, hn = bn;
            #pragma unroll
            for (int d = 0; d < 12; d++) {
                hr = fmaf(wr[d], h[d], hr);
                hz = fmaf(wz[d], h[d], hz);
                hn = fmaf(wn[d], h[d], hn);
            }
            float r = sigm2(gr + hr);
            float z = sigm2(gz + hz);
            float n = tanh2(fmaf(r, hn, gn));
            float hj = fmaf(z, hself - n, n);               // (1-z)*n + z*h
            hself = hj;
            #pragma unroll
            for (int d = 0; d < 12; d++) h[d] = __shfl(hj, src + d, 64);
        }
    }

    // ---- GRU2 (emit h every step); gi2 = gi1 + pegi[k] ----
    float4 speb[8];
    #pragma unroll
    for (int i = 0; i < 8; i++) {
        buf[i]  = gp[(size_t)i * KSTR];
        speb[i] = pegi[i * 12 + ju];
    }
    float* ho = hout + (size_t)b * 1920;                    // [b][k][12]
    for (int ko = 0; ko < 160; ko += 8) {
        #pragma unroll
        for (int i = 0; i < 8; i++) {
            const int k = ko + i;
            float gr = bf2f(buf[i].x & 0xffffu) + speb[i].x;
            float gz = bf2f(buf[i].x >> 16)     + speb[i].y;
            float gn = bf2f(buf[i].y & 0xffffu) + speb[i].z;
            int kp = k + 8; kp = (kp > 159) ? 159 : kp;
            buf[i]  = gp[(size_t)kp * KSTR];
            speb[i] = pegi[kp * 12 + ju];
            float hr = 0.f, hz = 0.f, hn = bn;
            #pragma unroll
            for (int d = 0; d < 12; d++) {
                hr = fmaf(wr[d], h[d], hr);
                hz = fmaf(wz[d], h[d], hz);
                hn = fmaf(wn[d], h[d], hn);
            }
            float r = sigm2(gr + hr);
            float z = sigm2(gz + hz);
            float n = tanh2(fmaf(r, hn, gn));
            float hj = fmaf(z, hself - n, n);
            hself = hj;
            if (j < 12) ho[k * 12 + j] = hj;
            #pragma unroll
            for (int d = 0; d < 12; d++) h[d] = __shfl(hj, src + d, 64);
        }
    }
}

// ---------------------------------------------------------------
// Kernel 3: fold. Wc[k][d][o] = sum_h W1[k][d][h]*W2[k][h][o];
// bc[k][o] = sum_h b1[k][h]*W2[k][h][o] + b2[k][o].
// One thread per output cell (156 of 256 active), full 1024-dot.
// W1 is [12][1024] d-major (r4 bug: don't tile it as [h][12]!).
// Wcg[k][t]: t<144 -> Wc (d=t/12,o=t%12); t in 144..155 -> bc.
// grid 160 x 256.
// ---------------------------------------------------------------
__global__ __launch_bounds__(256) void k_fold(
    const float* __restrict__ W1, const float* __restrict__ b1,
    const float* __restrict__ W2, const float* __restrict__ b2,
    float* __restrict__ Wcg)
{
    const int k = blockIdx.x, t = threadIdx.x;
    if (t >= 156) return;
    const int o = (t < 144) ? (t % 12) : (t - 144);
    const float* va = (t < 144) ? (W1 + (size_t)k * 12288 + (size_t)(t / 12) * 1024)
                                : (b1 + (size_t)k * 1024);
    const float* vb = W2 + (size_t)k * 12288 + o;
    const float4* va4 = reinterpret_cast<const float4*>(va);
    float s0 = 0.f, s1 = 0.f, s2 = 0.f, s3 = 0.f;
    #pragma unroll 4
    for (int q = 0; q < 256; q++) {
        float4 a = va4[q];
        const float* vbq = vb + q * 48;
        s0 = fmaf(a.x, vbq[0],  s0);
        s1 = fmaf(a.y, vbq[12], s1);
        s2 = fmaf(a.z, vbq[24], s2);
        s3 = fmaf(a.w, vbq[36], s3);
    }
    float s = (s0 + s1) + (s2 + s3);
    if (t >= 144) s += b2[k * 12 + o];
    Wcg[k * 156 + t] = s;
}

// ---------------------------------------------------------------
// Kernel 4: apply, in-place on d_out. out[b,k*12+o] = h[b,k,:]@Wc[k] + bc[k].
// grid 160 x 256, 624 B LDS broadcast of Wc[k].
// ---------------------------------------------------------------
__global__ __launch_bounds__(256) void k_apply(
    const float* __restrict__ Wcg, float* __restrict__ out)
{
    const int k = blockIdx.x, t = threadIdx.x;
    __shared__ float sw[156];
    if (t < 156) sw[t] = Wcg[k * 156 + t];
    __syncthreads();

    for (int bb = t; bb < 1024; bb += 256) {
        float* hp = out + (size_t)bb * 1920 + k * 12;
        float4* h4 = reinterpret_cast<float4*>(hp);
        float4 a0 = h4[0], a1 = h4[1], a2 = h4[2];
        float hv[12] = {a0.x,a0.y,a0.z,a0.w, a1.x,a1.y,a1.z,a1.w, a2.x,a2.y,a2.z,a2.w};
        float ov[12];
        #pragma unroll
        for (int o = 0; o < 12; o++) {
            float s = sw[144 + o];
            #pragma unroll
            for (int d = 0; d < 12; d++) s = fmaf(hv[d], sw[d * 12 + o], s);
            ov[o] = s;
        }
        h4[0] = make_float4(ov[0], ov[1], ov[2],  ov[3]);
        h4[1] = make_float4(ov[4], ov[5], ov[6],  ov[7]);
        h4[2] = make_float4(ov[8], ov[9], ov[10], ov[11]);
    }
}

// ---------------------------------------------------------------
extern "C" void kernel_launch(void* const* d_in, const int* in_sizes, int n_in,
                              void* d_out, int out_size, void* d_ws, size_t ws_size,
                              hipStream_t stream)
{
    const float* x    = (const float*)d_in[0];
    const float* encW = (const float*)d_in[1];
    const float* encb = (const float*)d_in[2];
    const float* Wih  = (const float*)d_in[3];
    const float* Whh  = (const float*)d_in[4];
    const float* bih  = (const float*)d_in[5];
    const float* bhh  = (const float*)d_in[6];
    const float* W1   = (const float*)d_in[7];
    const float* b1   = (const float*)d_in[8];
    const float* W2   = (const float*)d_in[9];
    const float* b2   = (const float*)d_in[10];
    float* out = (float*)d_out;

    char* ws = (char*)d_ws;
    uint2*  gi   = (uint2*)(ws);
    float4* pegi = (float4*)(ws + OFF_PEGI);
    float*  Wcg  = (float*)(ws + OFF_WC);

    k_encode<<<dim3(4, 160), 256, 0, stream>>>(x, encW, encb, Wih, bih, bhh, gi, pegi);
    k_fold  <<<dim3(160),    256, 0, stream>>>(W1, b1, W2, b2, Wcg);
    k_recur <<<dim3(256),    64,  0, stream>>>(Whh, bhh, gi, pegi, out);
    k_apply <<<dim3(160),    256, 0, stream>>>(Wcg, out);
}